// Round 1
// baseline (707.020 us; speedup 1.0000x reference)
//
#include <hip/hip_runtime.h>

// CTC batch cost (Keras semantics): B=256, T=1024, C=128 (blank=last), U=100.
// One block per batch element; one thread per extended-label state (S=201).
// alpha recursion in base-2 log domain (v_exp_f32/v_log_f32 are natively exp2/log2).
// Double-buffered LDS for alpha + per-class log-probs; ONE barrier per time step.
// Depth-8 register prefetch pipeline hides HBM latency of the 512B class rows.

#define Bc 256
#define Tc 1024
#define Cc 128
#define Uc 100
#define Sc 201            // 2U+1
#define BLANKc 127
#define NEGc (-1.0e30f)
#define EPSc 1e-7f
#define PF 8
#define LN2f 0.69314718055994530942f

__global__ __launch_bounds__(256) void ctc_loss_kernel(
    const float* __restrict__ y_pred,     // [B,T,C] post-softmax probs
    const int*   __restrict__ y_true,     // [B,U]
    const int*   __restrict__ label_len,  // [B]
    float*       __restrict__ out)        // [B,1]
{
    __shared__ float lds_lp[2][Cc];       // log2(p+eps) per class, double-buffered
    __shared__ float lds_alpha[2][Sc + 2];// state s stored at index s+2; [0..1] = NEG pads

    const int b   = blockIdx.x;
    const int tid = threadIdx.x;
    const float* gp = y_pred + (size_t)b * Tc * Cc;

    // ---- per-thread state metadata (ext label + skip-allowed flag) ----
    int  ext  = BLANKc;
    bool skip = false;
    if (tid < Sc && (tid & 1)) {
        const int k   = (tid - 1) >> 1;
        const int lab = y_true[b * Uc + k];
        ext = lab;
        if (k > 0) {
            const int labm1 = y_true[b * Uc + k - 1];
            skip = (lab != labm1);          // labels are never blank (range [0,C-2])
        }
    }

    // NEG pads (written once; never overwritten since state writes go to s+2 >= 2)
    if (tid < 2) {
        lds_alpha[0][tid] = NEGc;
        lds_alpha[1][tid] = NEGc;
    }

    // ---- stage row 0 and fill the prefetch pipeline (rows 1..PF) ----
    float pre[PF];
    if (tid < Cc) {
        lds_lp[0][tid] = __log2f(gp[tid] + EPSc);
#pragma unroll
        for (int j = 0; j < PF; ++j)
            pre[j] = gp[(size_t)(1 + j) * Cc + tid];
    }
    __syncthreads();

    // ---- t = 0 init: only s=0 (blank) and s=1 (first label) reachable ----
    float alpha = NEGc;
    if (tid == 0)      alpha = lds_lp[0][BLANKc];
    else if (tid == 1) alpha = lds_lp[0][ext];
    if (tid < Sc) lds_alpha[0][tid + 2] = alpha;
    // published by the barrier inside the first loop iteration

    // ---- time recursion: one barrier per step ----
    auto step_body = [&](int tt, float& pre_j, bool pf) {
        const int cur = tt & 1, prv = cur ^ 1;
        if (tid < Cc) {
            const float v = pre_j;
            if (pf) {
                int nr = tt + PF; if (nr > Tc - 1) nr = Tc - 1;   // clamped prefetch
                pre_j = gp[(size_t)nr * Cc + tid];
            }
            lds_lp[cur][tid] = __log2f(v + EPSc);
        }
        __syncthreads();   // publishes lds_lp[cur] AND lds_alpha[prv] (written last iter)
        if (tid < Sc) {
            const float a1  = lds_alpha[prv][tid + 1];
            const float a2r = lds_alpha[prv][tid];
            const float a2  = skip ? a2r : NEGc;
            const float lp  = lds_lp[cur][ext];
            const float m   = fmaxf(fmaxf(alpha, a1), a2);
            const float sum = exp2f(alpha - m) + exp2f(a1 - m) + exp2f(a2 - m);
            alpha = m + __log2f(sum) + lp;
            lds_alpha[cur][tid + 2] = alpha;
        }
    };

    int t = 1;
    for (; t + PF <= Tc; t += PF) {        // covers t = 1 .. 1016 (127 x 8)
#pragma unroll
        for (int j = 0; j < PF; ++j)
            step_body(t + j, pre[j], true);
    }
#pragma unroll
    for (int j = 0; j < PF - 1; ++j)       // tail t = 1017 .. 1023, slots align: (t-1)%8 == j
        step_body(t + j, pre[j], false);

    __syncthreads();                        // publish final alpha (in lds_alpha[(T-1)&1] = [1])

    // ---- epilogue: loss = -ln2 * log2sumexp2(alpha[2L-1], alpha[2L]) ----
    if (tid == 0) {
        const int   L  = label_len[b];
        const float a1 = lds_alpha[(Tc - 1) & 1][2 * L - 1 + 2];
        const float a2 = lds_alpha[(Tc - 1) & 1][2 * L + 2];
        const float m  = fmaxf(a1, a2);
        const float r  = m + __log2f(exp2f(a1 - m) + exp2f(a2 - m));
        out[b] = -LN2f * r;
    }
}

extern "C" void kernel_launch(void* const* d_in, const int* in_sizes, int n_in,
                              void* d_out, int out_size, void* d_ws, size_t ws_size,
                              hipStream_t stream) {
    const float* y_pred    = (const float*)d_in[0];
    const int*   y_true    = (const int*)d_in[1];
    const int*   label_len = (const int*)d_in[2];
    float*       out       = (float*)d_out;
    ctc_loss_kernel<<<Bc, 256, 0, stream>>>(y_pred, y_true, label_len, out);
}

// Round 2
// 291.760 us; speedup vs baseline: 2.4233x; 2.4233x over previous
//
#include <hip/hip_runtime.h>

// CTC batch cost, linear-domain single-wave formulation.
// One wave (64 lanes) per batch element; lane L owns states 4L..4L+3 (S=201).
// alpha kept in linear space with a per-lane power-of-2 exponent e
// (true alpha = a * 2^e); renormalized every 4 steps. No __syncthreads in the
// time loop -> no vmcnt(0) barrier drain -> the PF=16 register prefetch
// pipeline actually hides HBM latency.
//
// Recursion (all from t-1 values):  h1 = A[4L-1] (one shfl_up; even states
// never skip so A[4L-2] is never needed):
//   n0 = (a0 + h1) * pb
//   n1 = (a1 + a0 + ms1*h1) * p_lab0
//   n2 = (a2 + a1) * pb
//   n3 = (a3 + a2 + ms3*a1) * p_lab1

#define Bc 256
#define Tc 1024
#define Cc 128
#define Uc 100
#define BLANKc 127
#define EPSc 1e-7f
#define PF 16
#define LN2f 0.69314718055994530942f

__global__ __launch_bounds__(64) void ctc_lin_kernel(
    const float* __restrict__ y_pred,     // [B,T,C] post-softmax probs
    const int*   __restrict__ y_true,     // [B,U]
    const int*   __restrict__ label_len,  // [B]
    float*       __restrict__ out)        // [B,1]
{
    __shared__ float shA[204];
    __shared__ int   shE[64];

    const int b    = blockIdx.x;
    const int lane = threadIdx.x;                  // 0..63
    const float* gp = y_pred + (size_t)b * (Tc * Cc);

    // ---- per-lane label classes & skip masks (time-invariant) ----
    const int k0  = 2 * lane, k1 = 2 * lane + 1;
    const int k0c = k0 < Uc ? k0 : Uc - 1;
    const int k1c = k1 < Uc ? k1 : Uc - 1;
    const int y0  = y_true[b * Uc + k0c];          // class of state 4L+1
    const int y1  = y_true[b * Uc + k1c];          // class of state 4L+3
    int ym1 = y0;
    if (lane > 0) ym1 = y_true[b * Uc + k0 - 1];   // k0-1 = 2L-1 <= 99 when L<=50
    const float ms1 = (lane > 0 && y0 != ym1) ? 1.0f : 0.0f;
    const float ms3 = (y1 != y0) ? 1.0f : 0.0f;
    const float mh  = (lane > 0) ? 1.0f : 0.0f;    // halo mask (lane 0 has no left)

    // ---- t = 0 init ----
    float a0 = 0.0f, a1 = 0.0f, a2 = 0.0f, a3 = 0.0f;
    if (lane == 0) {
        a0 = gp[BLANKc] + EPSc;                    // state 0 (blank)
        a1 = gp[y0] + EPSc;                        // state 1 (first label)
    }
    int e = 0;                                     // per-lane exponent

    // ---- fill prefetch pipeline: rows t = 1..PF ----
    float fB[PF], fL0[PF], fL1[PF];
    {
        const float* q = gp + Cc;
#pragma unroll
        for (int j = 0; j < PF; ++j) {
            fB[j]  = q[j * Cc + BLANKc];
            fL0[j] = q[j * Cc + y0];
            fL1[j] = q[j * Cc + y1];
        }
    }

    auto step = [&](float pbr, float p0r, float p1r) {
        const int   el  = __shfl_up(e, 1, 64);
        const float h1r = __shfl_up(a3, 1, 64);
        int d = el - e; d = d > 126 ? 126 : d;     // clamp: avoid inf blowup
        const float h1 = mh * ldexpf(h1r, d);      // A[4L-1] in this lane's units
        const float pb = pbr + EPSc, p0 = p0r + EPSc, p1 = p1r + EPSc;
        const float n0 = (a0 + h1) * pb;
        const float n1 = (a1 + a0 + ms1 * h1) * p0;
        const float n2 = (a2 + a1) * pb;
        const float n3 = (a3 + a2 + ms3 * a1) * p1;
        a0 = n0; a1 = n1; a2 = n2; a3 = n3;
        // dormant lanes track left neighbor's exponent (1 lane/step > frontier)
        const float sm = (a0 + a1) + (a2 + a3);
        if (!(sm > 0.0f)) e = el;
    };

    auto renorm = [&]() {
        const float m = fmaxf(fmaxf(a0, a1), fmaxf(a2, a3));
        int ex = (int)((__float_as_uint(m) >> 23) & 0xFF) - 127;
        ex = (m > 0.0f) ? ex : 0;
        a0 = ldexpf(a0, -ex); a1 = ldexpf(a1, -ex);
        a2 = ldexpf(a2, -ex); a3 = ldexpf(a3, -ex);
        e += ex;
    };

    // ---- main loop: t = 1..992 (62 chunks of 16), prefetch t+16 <= 1008 ----
    const float* nxt = gp + (size_t)(1 + PF) * Cc;
    for (int c = 0; c < 62; ++c) {
#pragma unroll
        for (int j = 0; j < PF; ++j) {
            const float pb = fB[j], p0 = fL0[j], p1 = fL1[j];
            fB[j]  = nxt[j * Cc + BLANKc];
            fL0[j] = nxt[j * Cc + y0];
            fL1[j] = nxt[j * Cc + y1];
            step(pb, p0, p1);
            if ((j & 3) == 3) renorm();
        }
        nxt += PF * Cc;
    }
    // ---- t = 993..1008: prefetch rows 1009..1023 (j < 15 only) ----
#pragma unroll
    for (int j = 0; j < PF; ++j) {
        const float pb = fB[j], p0 = fL0[j], p1 = fL1[j];
        if (j < PF - 1) {
            fB[j]  = nxt[j * Cc + BLANKc];
            fL0[j] = nxt[j * Cc + y0];
            fL1[j] = nxt[j * Cc + y1];
        }
        step(pb, p0, p1);
        if ((j & 3) == 3) renorm();
    }
    // ---- t = 1009..1023 (15 steps, slots 0..14, no prefetch) ----
#pragma unroll
    for (int j = 0; j < PF - 1; ++j) {
        step(fB[j], fL0[j], fL1[j]);
        if ((j & 3) == 3) renorm();
    }

    // ---- epilogue: loss = -ln( A[2L-1] + A[2L] ), A = a * 2^e ----
    if (lane < 51) {
        shA[4 * lane + 0] = a0; shA[4 * lane + 1] = a1;
        shA[4 * lane + 2] = a2; shA[4 * lane + 3] = a3;
        shE[lane] = e;
    }
    __syncthreads();                               // single wave; one-time cost
    if (lane == 0) {
        const int L  = label_len[b];
        const int s1 = 2 * L - 1, s2 = 2 * L;
        const float v1 = shA[s1], v2 = shA[s2];
        const int   e1 = shE[s1 >> 2], e2 = shE[s2 >> 2];
        const int   em = e1 > e2 ? e1 : e2;
        const float sum = ldexpf(v1, e1 - em) + ldexpf(v2, e2 - em);
        const float r   = __log2f(sum) + (float)em;
        out[b] = -LN2f * r;
    }
}

extern "C" void kernel_launch(void* const* d_in, const int* in_sizes, int n_in,
                              void* d_out, int out_size, void* d_ws, size_t ws_size,
                              hipStream_t stream) {
    const float* y_pred    = (const float*)d_in[0];
    const int*   y_true    = (const int*)d_in[1];
    const int*   label_len = (const int*)d_in[2];
    float*       out       = (float*)d_out;
    ctc_lin_kernel<<<Bc, 64, 0, stream>>>(y_pred, y_true, label_len, out);
}

// Round 6
// 267.044 us; speedup vs baseline: 2.6476x; 1.0926x over previous
//
#include <hip/hip_runtime.h>

// CTC batch cost, linear-domain, single wave per batch element, DIAGONAL SKEW.
// Lane L owns states 4L..4L+3 (S=201) and at wave-step n computes time
// t = n - L. The left halo A[4L-1](t-1) is the left lane's a3 produced at
// wave-step n-2 -> each __shfl_up has 2 steps (~150cyc) of slack and leaves
// the critical path (round 2 had 2 serialized ~120cyc bpermutes per step).
// DPP lane-shift abandoned: rounds 3/4/5 showed update_dpp is unreliable on
// this stack; __shfl_up was exact (round 2, absmax 0.0).
//
// Probabilities: rows staged via a single-wave LDS circular buffer (128 slots
// x 130f padded stride): 1 coalesced float2 global load + 1 ds_write per step
// (8-deep VGPR queue, 15-step write->read distance), 3x ds_read_b32 consume.
// Single wave -> LDS ops are program-ordered; NO barrier in the loop.
//
// Recurrence (exactly round 2's, absmax 0.0):
//   n0 = (a0 + h1) * pb
//   n1 = (a1 + a0 + ms1*h1) * p_lab0
//   n2 = (a2 + a1) * pb
//   n3 = (a3 + a2 + ms3*a1) * p_lab1
// with per-lane exponent e (true alpha = a*2^e), renorm every 4 steps.

#define Bc 256
#define Tc 1024
#define Cc 128
#define Uc 100
#define BLANKc 127
#define EPSc 1e-7f
#define LN2f 0.69314718055994530942f
#define RSTRIDE 130          // floats per row slot (even -> 8B-aligned float2)
#define NSLOT 128            // circular buffer depth (needs >= 80 live rows)
#define QD 8                 // global->LDS staging queue depth

__global__ __launch_bounds__(64) void ctc_skew_kernel(
    const float* __restrict__ y_pred,     // [B,T,C] post-softmax probs
    const int*   __restrict__ y_true,     // [B,U]
    const int*   __restrict__ label_len,  // [B]
    float*       __restrict__ out)        // [B,1]
{
    __shared__ float rowbuf[NSLOT * RSTRIDE];   // 66560 B circular row cache
    __shared__ float shA[204];
    __shared__ int   shE[64];

    const int b    = blockIdx.x;
    const int lane = threadIdx.x;                  // 0..63
    const float* gp = y_pred + (size_t)b * (Tc * Cc);

    // ---- per-lane label classes & skip masks (time-invariant) ----
    const int k0  = 2*lane, k1 = 2*lane+1;
    const int k0c = k0 < Uc ? k0 : Uc-1;
    const int k1c = k1 < Uc ? k1 : Uc-1;
    const int y0  = y_true[b*Uc + k0c];            // class of state 4L+1
    const int y1  = y_true[b*Uc + k1c];            // class of state 4L+3
    int ym1 = y0;
    if (lane > 0) ym1 = y_true[b*Uc + k0 - 1];
    const float ms1 = (lane > 0 && y0 != ym1) ? 1.0f : 0.0f;
    const float ms3 = (y1 != y0) ? 1.0f : 0.0f;
    const float mh  = (lane > 0) ? 1.0f : 0.0f;    // lane 0 has no left halo

    // ---- t=0 init (only lane 0 holds mass) ----
    float a0=0.f, a1=0.f, a2=0.f, a3=0.f;
    if (lane == 0) { a0 = gp[BLANKc]+EPSc; a1 = gp[y0]+EPSc; }
    int e = 0;

    // ---- pre-stage rows 0..15 into LDS (coalesced float4 reads) ----
#pragma unroll
    for (int i = 0; i < 8; ++i) {
        const int f4  = i*64 + lane;               // 512 float4 across 16 rows
        const int row = f4 >> 5;                   // 32 float4 per row
        const int c4  = (f4 & 31) * 4;
        const float4 v = *(const float4*)(gp + row*Cc + c4);
        float* dst = &rowbuf[row*RSTRIDE + c4];
        dst[0]=v.x; dst[1]=v.y; dst[2]=v.z; dst[3]=v.w;
    }
    // single wave: LDS writes/reads are program-ordered; no barrier needed.

    // ---- staging queue: rows 16..23 in flight ----
    float2 Q[QD];
#pragma unroll
    for (int k = 0; k < QD; ++k)
        Q[k] = *(const float2*)(gp + (16+k)*Cc + lane*2);

    // ---- halo queue (2-step shuffle latency); initial a3=0, e=0 everywhere
    float q2a = 0.f, q1a = 0.f;
    int   q2e = 0,   q1e = 0;

    auto body = [&](int n, int j, bool fzp) {
        // -- consume this step's probs: lane L reads row (n - L), clamped --
        const int rr = n - lane;
        const int rc = (rr < 0 ? 0 : rr) & (NSLOT-1);
        const float* rowp = &rowbuf[rc * RSTRIDE];
        const float pbr = rowp[BLANKc];
        const float p0r = rowp[y0];
        const float p1r = rowp[y1];
        // -- stage: ds_write row n+15 (loaded 8 steps ago), reload row n+23 --
        const int j8 = (n-1) & (QD-1);
        const int ws = (n+15) & (NSLOT-1);
        *(float2*)&rowbuf[ws*RSTRIDE + lane*2] = Q[j8];
        int lr = n+23; lr = lr > Tc-1 ? Tc-1 : lr;
        Q[j8] = *(const float2*)(gp + lr*Cc + lane*2);
        // -- halo issued 2 wave-steps ago = left's state after its t-1 --
        const float h1r = q2a; const int el = q2e;
        q2a = q1a; q2e = q1e;
        int d = el - e; d = d > 126 ? 126 : d;     // clamp: avoid inf blowup
        const float h1 = mh * ldexpf(h1r, d);
        const float pb = pbr + EPSc, p0 = p0r + EPSc, p1 = p1r + EPSc;
        const float n0 = (a0 + h1) * pb;
        const float n1 = (a1 + a0 + ms1*h1) * p0;
        const float n2 = (a2 + a1) * pb;
        const float n3 = (a3 + a2 + ms3*a1) * p1;
        const float sm = (n0+n1)+(n2+n3);
        const int   en = (sm > 0.0f) ? e : el;     // dormant lanes track left e
        bool upd = true;
        if (fzp) upd = (lane >= n - (Tc-1));       // freeze lanes past t=1023
        if (upd) { a0=n0; a1=n1; a2=n2; a3=n3; e=en; }
        if ((j & 3) == 3) {                        // renorm (preserves a*2^e)
            const float m = fmaxf(fmaxf(a0,a1), fmaxf(a2,a3));
            int ex = (int)((__float_as_uint(m) >> 23) & 0xFF) - 127;
            ex = (m > 0.0f) ? ex : 0;
            a0 = ldexpf(a0,-ex); a1 = ldexpf(a1,-ex);
            a2 = ldexpf(a2,-ex); a3 = ldexpf(a3,-ex);
            e += ex;
        }
        // -- issue halo for wave-step n+2 (a3,e pair post-renorm: consistent)
        q1a = __shfl_up(a3, 1, 64);
        q1e = __shfl_up(e , 1, 64);
    };

    // ---- wave-steps n = 1..1086 (= 1023 times + 63 drain) ----
    int n = 1;
    for (int c = 0; c < 63; ++c) {                 // n = 1..1008: no freeze
#pragma unroll
        for (int j = 0; j < 16; ++j) { body(n, j, false); ++n; }
    }
    for (int c = 0; c < 4; ++c) {                  // n = 1009..1072 (freeze
#pragma unroll                                     //  predicate inert <1024)
        for (int j = 0; j < 16; ++j) { body(n, j, true); ++n; }
    }
#pragma unroll
    for (int j = 0; j < 14; ++j) { body(n, j, true); ++n; }  // n = 1073..1086

    // ---- epilogue: loss = -ln( A[2L-1] + A[2L] ), A = a * 2^e ----
    if (lane < 51) {
        shA[4*lane+0] = a0; shA[4*lane+1] = a1;
        shA[4*lane+2] = a2; shA[4*lane+3] = a3;
        shE[lane] = e;
    }
    __syncthreads();                               // one-time, post-loop
    if (lane == 0) {
        const int L  = label_len[b];
        const int s1 = 2*L - 1, s2 = 2*L;
        const float v1 = shA[s1], v2 = shA[s2];
        const int   e1 = shE[s1 >> 2], e2 = shE[s2 >> 2];
        const int   em = e1 > e2 ? e1 : e2;
        const float sum = ldexpf(v1, e1-em) + ldexpf(v2, e2-em);
        const float r   = __log2f(sum) + (float)em;
        out[b] = -LN2f * r;
    }
}

extern "C" void kernel_launch(void* const* d_in, const int* in_sizes, int n_in,
                              void* d_out, int out_size, void* d_ws, size_t ws_size,
                              hipStream_t stream) {
    const float* y_pred    = (const float*)d_in[0];
    const int*   y_true    = (const int*)d_in[1];
    const int*   label_len = (const int*)d_in[2];
    float*       out       = (float*)d_out;
    ctc_skew_kernel<<<Bc, 64, 0, stream>>>(y_pred, y_true, label_len, out);
}